// Round 2
// baseline (313.909 us; speedup 1.0000x reference)
//
#include <hip/hip_runtime.h>

typedef __bf16 bf16;
typedef bf16 bf16x8 __attribute__((ext_vector_type(8)));
typedef bf16 bf16x4 __attribute__((ext_vector_type(4)));
typedef float f32x4 __attribute__((ext_vector_type(4)));
typedef unsigned short ushort;
typedef ushort ushort4v __attribute__((ext_vector_type(4)));

#define BB 8192   // batch
#define NN 2048   // nodes

// ---------------------------------------------------------------------------
__device__ __forceinline__ void async16(const void* g, void* l) {
    __builtin_amdgcn_global_load_lds(
        (__attribute__((address_space(1))) void*)(void*)g,
        (__attribute__((address_space(3))) void*)l,
        16, 0, 0);
}

// ---------------------------------------------------------------------------
// K1 v2: gather-conv, 2 batch rows per block.
//   V[bb][g] = relu(cb + sum_w cw[0][w]*x[bb,adj[g,w]] + cw[1][w]*label[bb,adj[g,w]])
// x/label rows staged in SEPARATE fp32 LDS arrays (bank = node%32, full spread).
// adj rows register-resident, reused across both bb. Each thread owns 8
// consecutive g -> one bf16x8 (16B) store per row.
__global__ __launch_bounds__(256) void conv_gather(
    const float* __restrict__ x, const float* __restrict__ label,
    const int* __restrict__ adj, const float* __restrict__ cw,
    const float* __restrict__ cb, bf16* __restrict__ V) {
    __shared__ float sx[2][NN];   // 16 KB
    __shared__ float sl[2][NN];   // 16 KB
    const int bb0 = blockIdx.x * 2;
    const int t   = threadIdx.x;

#pragma unroll
    for (int rr = 0; rr < 2; ++rr) {
        const float4* xr = (const float4*)(x     + (size_t)(bb0 + rr) * NN);
        const float4* lr = (const float4*)(label + (size_t)(bb0 + rr) * NN);
#pragma unroll
        for (int q = 0; q < 2; ++q) {
            int i = q * 256 + t;                 // float4 index, 512 per row
            ((float4*)sx[rr])[i] = xr[i];
            ((float4*)sl[rr])[i] = lr[i];
        }
    }
    const float w0 = cw[0], w1 = cw[1], w2 = cw[2], w3 = cw[3];
    const float w4 = cw[4], w5 = cw[5], w6 = cw[6], w7 = cw[7];
    const float bias = cb[0];

    // adj rows for this thread's 8 consecutive g, register-resident
    const int4* adj4 = (const int4*)adj;
    int4 a[8];
#pragma unroll
    for (int j = 0; j < 8; ++j) a[j] = adj4[t * 8 + j];

    __syncthreads();

#pragma unroll
    for (int rr = 0; rr < 2; ++rr) {
        const float* px = sx[rr];
        const float* pl = sl[rr];
        bf16 o[8];
#pragma unroll
        for (int j = 0; j < 8; ++j) {
            int4 aa = a[j];
            float v = bias
                    + w0 * px[aa.x] + w1 * px[aa.y] + w2 * px[aa.z] + w3 * px[aa.w]
                    + w4 * pl[aa.x] + w5 * pl[aa.y] + w6 * pl[aa.z] + w7 * pl[aa.w];
            o[j] = (bf16)fmaxf(v, 0.0f);
        }
        *(bf16x8*)(V + (size_t)(bb0 + rr) * NN + t * 8) = *(const bf16x8*)o;
    }
}

// ---------------------------------------------------------------------------
// Kw v2: lin_w f32 -> bf16, 8 floats/thread, one 16B store.
__global__ __launch_bounds__(256) void cvtw(const float* __restrict__ W,
                                            bf16* __restrict__ Wb) {
    size_t i = (size_t)blockIdx.x * 256 + threadIdx.x;   // group of 8 floats
    float4 v0 = ((const float4*)W)[i * 2 + 0];
    float4 v1 = ((const float4*)W)[i * 2 + 1];
    bf16x8 o;
    o[0] = (bf16)v0.x; o[1] = (bf16)v0.y; o[2] = (bf16)v0.z; o[3] = (bf16)v0.w;
    o[4] = (bf16)v1.x; o[5] = (bf16)v1.y; o[6] = (bf16)v1.z; o[7] = (bf16)v1.w;
    ((bf16x8*)Wb)[i] = o;
}

// ---------------------------------------------------------------------------
// K2 v2: transpose V (8192 x 2048 bf16) -> Y2 flat == Vt (2048 x 8192).
// 64x64 tile, ushort4 (8B/lane) on BOTH global sides, LDS bounce with pad.
__global__ __launch_bounds__(256) void transp(const ushort* __restrict__ V,
                                              ushort* __restrict__ Y) {
    __shared__ ushort tile[64][68];   // pad 4 shorts: keeps 8B align, spreads banks
    const int g0 = blockIdx.x * 64;   // V col / Y row
    const int p0 = blockIdx.y * 64;   // V row / Y col
    const int c  = threadIdx.x & 15;  // 4-col group
    const int r4 = threadIdx.x >> 4;  // 0..15

#pragma unroll
    for (int pass = 0; pass < 4; ++pass) {
        int r = pass * 16 + r4;
        ushort4v v = *(const ushort4v*)(V + (size_t)(p0 + r) * NN + g0 + c * 4);
        *(ushort4v*)&tile[r][c * 4] = v;
    }
    __syncthreads();
#pragma unroll
    for (int pass = 0; pass < 4; ++pass) {
        int r = pass * 16 + r4;       // Y row within tile (g dim)
        ushort4v o;
        o.x = tile[c * 4 + 0][r];
        o.y = tile[c * 4 + 1][r];
        o.z = tile[c * 4 + 2][r];
        o.w = tile[c * 4 + 3][r];
        *(ushort4v*)(Y + (size_t)(g0 + r) * BB + p0 + c * 4) = o;
    }
}

// ---------------------------------------------------------------------------
// K3: unchanged m97-structure GEMM. out = A(8192x2048) * W(2048x2048)^T + bias.
__global__ __launch_bounds__(256) void gemm_bt(
    const bf16* __restrict__ A, const bf16* __restrict__ W,
    const float* __restrict__ bias, float* __restrict__ out) {
    __shared__ __attribute__((aligned(16))) bf16 sA[128 * 32];
    __shared__ __attribute__((aligned(16))) bf16 sB[128 * 32];

    const int t    = threadIdx.x;
    const int lane = t & 63;
    const int wv   = t >> 6;
    const int wm   = wv & 1;
    const int wn   = wv >> 1;
    const int m0   = blockIdx.x * 128;
    const int n0   = blockIdx.y * 128;

    f32x4 acc[4][4] = {};

    const int r  = t >> 2;
    const int c8 = (t & 3) * 8;
    const bf16* gA0 = A + (size_t)(m0 + r)      * 2048 + c8;
    const bf16* gA1 = A + (size_t)(m0 + r + 64) * 2048 + c8;
    const bf16* gB0 = W + (size_t)(n0 + r)      * 2048 + c8;
    const bf16* gB1 = W + (size_t)(n0 + r + 64) * 2048 + c8;
    bf16* lA0 = sA + (wv * 16)      * 32;
    bf16* lA1 = sA + (64 + wv * 16) * 32;
    bf16* lB0 = sB + (wv * 16)      * 32;
    bf16* lB1 = sB + (64 + wv * 16) * 32;

    const int quad = lane >> 4;
    const int l16  = lane & 15;
    const bf16* fA = sA + (wm * 64 + l16) * 32 + quad * 8;
    const bf16* fB = sB + (wn * 64 + l16) * 32 + quad * 8;

    for (int k0 = 0; k0 < 2048; k0 += 32) {
        async16(gA0 + k0, lA0);
        async16(gA1 + k0, lA1);
        async16(gB0 + k0, lB0);
        async16(gB1 + k0, lB1);
        __syncthreads();

        bf16x8 af[4], bfr[4];
#pragma unroll
        for (int i = 0; i < 4; ++i) af[i]  = *(const bf16x8*)(fA + i * 16 * 32);
#pragma unroll
        for (int j = 0; j < 4; ++j) bfr[j] = *(const bf16x8*)(fB + j * 16 * 32);
#pragma unroll
        for (int i = 0; i < 4; ++i)
#pragma unroll
            for (int j = 0; j < 4; ++j)
                acc[i][j] = __builtin_amdgcn_mfma_f32_16x16x32_bf16(
                    af[i], bfr[j], acc[i][j], 0, 0, 0);
        __syncthreads();
    }

#pragma unroll
    for (int j = 0; j < 4; ++j) {
        int col = n0 + wn * 64 + j * 16 + l16;
        float bcol = bias[col];
#pragma unroll
        for (int i = 0; i < 4; ++i) {
            int rowb = m0 + wm * 64 + i * 16 + quad * 4;
#pragma unroll
            for (int rr = 0; rr < 4; ++rr) {
                out[(size_t)(rowb + rr) * 2048 + col] = acc[i][j][rr] + bcol;
            }
        }
    }
}

// ---------------------------------------------------------------------------
extern "C" void kernel_launch(void* const* d_in, const int* in_sizes, int n_in,
                              void* d_out, int out_size, void* d_ws, size_t ws_size,
                              hipStream_t stream) {
    (void)in_sizes; (void)n_in; (void)out_size; (void)ws_size;
    const float* x     = (const float*)d_in[0];
    const float* label = (const float*)d_in[1];
    const int*   adj   = (const int*)d_in[2];
    const float* cw    = (const float*)d_in[3];
    const float* cb    = (const float*)d_in[4];
    const float* lw    = (const float*)d_in[5];
    const float* lb    = (const float*)d_in[6];
    float* out = (float*)d_out;

    // scratch: V (32MB) in d_out (overwritten by GEMM), Y2 at ws, Wb at ws+32MB
    bf16* V  = (bf16*)d_out;
    bf16* Y2 = (bf16*)d_ws;
    bf16* Wb = (bf16*)((char*)d_ws + (size_t)2048 * 8192 * 2);

    conv_gather<<<BB / 2, 256, 0, stream>>>(x, label, adj, cw, cb, V);
    cvtw<<<2048, 256, 0, stream>>>(lw, Wb);
    transp<<<dim3(32, 128), 256, 0, stream>>>((const ushort*)V, (ushort*)Y2);
    gemm_bt<<<dim3(64, 16), 256, 0, stream>>>(Y2, Wb, lb, out);
}

// Round 4
// 281.731 us; speedup vs baseline: 1.1142x; 1.1142x over previous
//
#include <hip/hip_runtime.h>

typedef __bf16 bf16;
typedef bf16 bf16x8 __attribute__((ext_vector_type(8)));
typedef float f32x4 __attribute__((ext_vector_type(4)));
typedef unsigned short ushort;
typedef ushort ushort4v __attribute__((ext_vector_type(4)));

#define BB 8192   // batch
#define NN 2048   // nodes

// ---------------------------------------------------------------------------
__device__ __forceinline__ void async16(const void* g, void* l) {
    __builtin_amdgcn_global_load_lds(
        (__attribute__((address_space(1))) void*)(void*)g,
        (__attribute__((address_space(3))) void*)l,
        16, 0, 0);
}

// ---------------------------------------------------------------------------
// K1 v3: gather-conv, 2 batch rows/block, nodes packed (x0,l0,x1,l1) in one
// float4 -> ONE ds_read_b128 per node serves both rows.
__global__ __launch_bounds__(256) void conv_gather(
    const float* __restrict__ x, const float* __restrict__ label,
    const int* __restrict__ adj, const float* __restrict__ cw,
    const float* __restrict__ cb, bf16* __restrict__ V) {
    __shared__ float4 sxl[NN];   // 32 KB
    const int bb0 = blockIdx.x * 2;
    const int t   = threadIdx.x;

    const float4* x0 = (const float4*)(x     + (size_t)bb0 * NN);
    const float4* x1 = (const float4*)(x     + (size_t)(bb0 + 1) * NN);
    const float4* l0 = (const float4*)(label + (size_t)bb0 * NN);
    const float4* l1 = (const float4*)(label + (size_t)(bb0 + 1) * NN);
#pragma unroll
    for (int q = 0; q < 2; ++q) {
        int i = q * 256 + t;             // float4 index, 512 per row
        float4 a = x0[i], b = l0[i], c = x1[i], d = l1[i];
        sxl[i*4+0] = make_float4(a.x, b.x, c.x, d.x);
        sxl[i*4+1] = make_float4(a.y, b.y, c.y, d.y);
        sxl[i*4+2] = make_float4(a.z, b.z, c.z, d.z);
        sxl[i*4+3] = make_float4(a.w, b.w, c.w, d.w);
    }
    const float w0 = cw[0], w1 = cw[1], w2 = cw[2], w3 = cw[3];
    const float w4 = cw[4], w5 = cw[5], w6 = cw[6], w7 = cw[7];
    const float bias = cb[0];

    const int4* adj4 = (const int4*)adj;
    int4 a[8];
#pragma unroll
    for (int j = 0; j < 8; ++j) a[j] = adj4[t * 8 + j];

    __syncthreads();

    bf16 o0[8], o1[8];
#pragma unroll
    for (int j = 0; j < 8; ++j) {
        int4 aa = a[j];
        float4 p0 = sxl[aa.x];
        float4 p1 = sxl[aa.y];
        float4 p2 = sxl[aa.z];
        float4 p3 = sxl[aa.w];
        float v0 = bias
                 + w0 * p0.x + w1 * p1.x + w2 * p2.x + w3 * p3.x
                 + w4 * p0.y + w5 * p1.y + w6 * p2.y + w7 * p3.y;
        float v1 = bias
                 + w0 * p0.z + w1 * p1.z + w2 * p2.z + w3 * p3.z
                 + w4 * p0.w + w5 * p1.w + w6 * p2.w + w7 * p3.w;
        o0[j] = (bf16)fmaxf(v0, 0.0f);
        o1[j] = (bf16)fmaxf(v1, 0.0f);
    }
    *(bf16x8*)(V + (size_t)bb0 * NN + t * 8)       = *(const bf16x8*)o0;
    *(bf16x8*)(V + (size_t)(bb0 + 1) * NN + t * 8) = *(const bf16x8*)o1;
}

// ---------------------------------------------------------------------------
// K2: fused (a) transpose V (8192x2048 bf16) -> Y2 (2048x8192), blocks 0..4095
//           (b) lin_w f32 -> bf16 (4.19M floats),               blocks 4096..6143
//               (2048 floats per block -> 2048 blocks; was 1024 = the R3 bug)
__global__ __launch_bounds__(256) void transp_cvtw(
    const ushort* __restrict__ V, ushort* __restrict__ Y,
    const float* __restrict__ W, bf16* __restrict__ Wb) {
    const int b = blockIdx.x;
    if (b >= 4096) {
        size_t i = (size_t)(b - 4096) * 256 + threadIdx.x;
        float4 v0 = ((const float4*)W)[i * 2 + 0];
        float4 v1 = ((const float4*)W)[i * 2 + 1];
        bf16x8 o;
        o[0] = (bf16)v0.x; o[1] = (bf16)v0.y; o[2] = (bf16)v0.z; o[3] = (bf16)v0.w;
        o[4] = (bf16)v1.x; o[5] = (bf16)v1.y; o[6] = (bf16)v1.z; o[7] = (bf16)v1.w;
        ((bf16x8*)Wb)[i] = o;
        return;
    }
    __shared__ ushort tile[64][68];
    const int g0 = (b & 31) * 64;    // V col / Y row
    const int p0 = (b >> 5) * 64;    // V row / Y col
    const int c  = threadIdx.x & 15;
    const int r4 = threadIdx.x >> 4;

#pragma unroll
    for (int pass = 0; pass < 4; ++pass) {
        int r = pass * 16 + r4;
        ushort4v v = *(const ushort4v*)(V + (size_t)(p0 + r) * NN + g0 + c * 4);
        *(ushort4v*)&tile[r][c * 4] = v;
    }
    __syncthreads();
#pragma unroll
    for (int pass = 0; pass < 4; ++pass) {
        int r = pass * 16 + r4;
        ushort4v o;
        o.x = tile[c * 4 + 0][r];
        o.y = tile[c * 4 + 1][r];
        o.z = tile[c * 4 + 2][r];
        o.w = tile[c * 4 + 3][r];
        *(ushort4v*)(Y + (size_t)(g0 + r) * BB + p0 + c * 4) = o;
    }
}

// ---------------------------------------------------------------------------
// K3: out(8192x2048) = A * W^T + bias.  BK=64 as TWO m97-style 128x32
// sub-buffers (half the barrier drains vs BK=32).
__global__ __launch_bounds__(256) void gemm_bt(
    const bf16* __restrict__ A, const bf16* __restrict__ W,
    const float* __restrict__ bias, float* __restrict__ out) {
    __shared__ __attribute__((aligned(16))) bf16 sA[2][128 * 32];
    __shared__ __attribute__((aligned(16))) bf16 sB[2][128 * 32];

    const int t    = threadIdx.x;
    const int lane = t & 63;
    const int wv   = t >> 6;
    const int wm   = wv & 1;
    const int wn   = wv >> 1;
    const int m0   = blockIdx.x * 128;
    const int n0   = blockIdx.y * 128;

    f32x4 acc[4][4] = {};

    const int r  = t >> 2;
    const int c8 = (t & 3) * 8;
    const bf16* gA0 = A + (size_t)(m0 + r)      * 2048 + c8;
    const bf16* gA1 = A + (size_t)(m0 + r + 64) * 2048 + c8;
    const bf16* gB0 = W + (size_t)(n0 + r)      * 2048 + c8;
    const bf16* gB1 = W + (size_t)(n0 + r + 64) * 2048 + c8;
    bf16* lA0[2], *lA1[2], *lB0[2], *lB1[2];
#pragma unroll
    for (int s = 0; s < 2; ++s) {
        lA0[s] = sA[s] + (wv * 16)      * 32;
        lA1[s] = sA[s] + (64 + wv * 16) * 32;
        lB0[s] = sB[s] + (wv * 16)      * 32;
        lB1[s] = sB[s] + (64 + wv * 16) * 32;
    }

    const int quad = lane >> 4;
    const int l16  = lane & 15;
    const int foff = (wm * 64 + l16) * 32 + quad * 8;
    const int goff = (wn * 64 + l16) * 32 + quad * 8;

    for (int k0 = 0; k0 < 2048; k0 += 64) {
#pragma unroll
        for (int s = 0; s < 2; ++s) {
            async16(gA0 + k0 + s * 32, lA0[s]);
            async16(gA1 + k0 + s * 32, lA1[s]);
            async16(gB0 + k0 + s * 32, lB0[s]);
            async16(gB1 + k0 + s * 32, lB1[s]);
        }
        __syncthreads();

#pragma unroll
        for (int s = 0; s < 2; ++s) {
            const bf16* fA = sA[s] + foff;
            const bf16* fB = sB[s] + goff;
            bf16x8 af[4], bfr[4];
#pragma unroll
            for (int i = 0; i < 4; ++i) af[i]  = *(const bf16x8*)(fA + i * 16 * 32);
#pragma unroll
            for (int j = 0; j < 4; ++j) bfr[j] = *(const bf16x8*)(fB + j * 16 * 32);
#pragma unroll
            for (int i = 0; i < 4; ++i)
#pragma unroll
                for (int j = 0; j < 4; ++j)
                    acc[i][j] = __builtin_amdgcn_mfma_f32_16x16x32_bf16(
                        af[i], bfr[j], acc[i][j], 0, 0, 0);
        }
        __syncthreads();
    }

#pragma unroll
    for (int j = 0; j < 4; ++j) {
        int col = n0 + wn * 64 + j * 16 + l16;
        float bcol = bias[col];
#pragma unroll
        for (int i = 0; i < 4; ++i) {
            int rowb = m0 + wm * 64 + i * 16 + quad * 4;
#pragma unroll
            for (int rr = 0; rr < 4; ++rr) {
                out[(size_t)(rowb + rr) * 2048 + col] = acc[i][j][rr] + bcol;
            }
        }
    }
}

// ---------------------------------------------------------------------------
extern "C" void kernel_launch(void* const* d_in, const int* in_sizes, int n_in,
                              void* d_out, int out_size, void* d_ws, size_t ws_size,
                              hipStream_t stream) {
    (void)in_sizes; (void)n_in; (void)out_size; (void)ws_size;
    const float* x     = (const float*)d_in[0];
    const float* label = (const float*)d_in[1];
    const int*   adj   = (const int*)d_in[2];
    const float* cw    = (const float*)d_in[3];
    const float* cb    = (const float*)d_in[4];
    const float* lw    = (const float*)d_in[5];
    const float* lb    = (const float*)d_in[6];
    float* out = (float*)d_out;

    // scratch: V (32MB) in d_out (overwritten by GEMM), Y2 at ws, Wb at ws+32MB
    bf16* V  = (bf16*)d_out;
    bf16* Y2 = (bf16*)d_ws;
    bf16* Wb = (bf16*)((char*)d_ws + (size_t)2048 * 8192 * 2);

    conv_gather<<<BB / 2, 256, 0, stream>>>(x, label, adj, cw, cb, V);
    transp_cvtw<<<6144, 256, 0, stream>>>((const ushort*)V, (ushort*)Y2,
                                          lw, Wb);
    gemm_bt<<<dim3(64, 16), 256, 0, stream>>>(Y2, Wb, lb, out);
}